// Round 1
// baseline (414.230 us; speedup 1.0000x reference)
//
#include <hip/hip_runtime.h>

// ---- problem constants ----
#define CC   192                 // C
#define C3   576                 // 3C
#define HH   64
#define WW   64
#define HWP  4096                // H*W
#define BB   8
#define DH   48                  // C/HEADS
#define QKV_B (C3*HWP)           // 2359296 floats per batch of qkv tensor
#define X_B   (CC*HWP)           // 786432 floats per batch of x
#define OUT_HALF ((size_t)BB*X_B)// 6291456

// ============================================================
// 1x1 conv = per-batch GEMM: Out(576 x 4096) = W(576x192) * In(192x4096)
// block: 256 thr, tile 32 oc x 128 p, K-chunks of 32 staged in LDS
// ============================================================
__global__ __launch_bounds__(256) void conv1x1_kernel(const float* __restrict__ in,
    const float* __restrict__ wq, float* __restrict__ out)
{
    __shared__ float It[32][128];
    __shared__ float Wt[32][36];   // pad 36 (mult of 4 -> aligned float4 rows)
    const int b = blockIdx.z, oc0 = blockIdx.y * 32, p0 = blockIdx.x * 128;
    const int t = threadIdx.x;
    const int tx = t & 31, ty = t >> 5;
    const float* inb = in + (size_t)b * X_B;
    float acc[4][4] = {};
    for (int c0 = 0; c0 < CC; c0 += 32) {
        #pragma unroll
        for (int i = 0; i < 4; i++) {
            int f = t + 256 * i;              // float4 units, 1024 total
            int r = f >> 5, c4 = f & 31;
            *(float4*)&It[r][c4 * 4] =
                *(const float4*)(inb + (c0 + r) * HWP + p0 + c4 * 4);
        }
        {
            int oc = t >> 3, c4 = t & 7;      // 32 oc x 8 float4
            float4 wv = *(const float4*)(wq + (oc0 + oc) * CC + c0 + c4 * 4);
            Wt[oc][c4*4+0] = wv.x; Wt[oc][c4*4+1] = wv.y;
            Wt[oc][c4*4+2] = wv.z; Wt[oc][c4*4+3] = wv.w;
        }
        __syncthreads();
        #pragma unroll
        for (int kc = 0; kc < 32; kc += 4) {
            float4 wv[4];
            #pragma unroll
            for (int j = 0; j < 4; j++) wv[j] = *(float4*)&Wt[ty*4+j][kc];
            #pragma unroll
            for (int kk = 0; kk < 4; kk++) {
                float4 a = *(float4*)&It[kc+kk][tx*4];
                #pragma unroll
                for (int j = 0; j < 4; j++) {
                    float w = (&wv[j].x)[kk];
                    acc[j][0] += w * a.x; acc[j][1] += w * a.y;
                    acc[j][2] += w * a.z; acc[j][3] += w * a.w;
                }
            }
        }
        __syncthreads();
    }
    float* ob = out + (size_t)b * QKV_B + oc0 * HWP + p0;
    #pragma unroll
    for (int j = 0; j < 4; j++) {
        *(float4*)(ob + (ty*4 + j) * HWP + tx * 4) =
            make_float4(acc[j][0], acc[j][1], acc[j][2], acc[j][3]);
    }
}

// ============================================================
// depthwise 3x3, pad 1. one block per (b,ch) 64x64 plane staged in LDS
// ============================================================
__global__ __launch_bounds__(256) void dw3x3_kernel(const float* __restrict__ in,
    const float* __restrict__ wd, float* __restrict__ out)
{
    __shared__ float P[HWP];
    const int bc = blockIdx.x;          // b*576 + ch
    const int ch = bc % C3;
    const int t = threadIdx.x;
    const float* ip = in + (size_t)bc * HWP;
    float wr[9];
    #pragma unroll
    for (int k = 0; k < 9; k++) wr[k] = wd[ch * 9 + k];
    #pragma unroll
    for (int i = 0; i < 4; i++) {
        int f = t + 256 * i;
        *(float4*)&P[f * 4] = *(const float4*)(ip + f * 4);
    }
    __syncthreads();
    float* op = out + (size_t)bc * HWP;
    #pragma unroll
    for (int i = 0; i < 4; i++) {
        int u = t + 256 * i;            // float4 unit
        int y0 = u >> 4;                // (u*4)/64
        int x0 = (u & 15) * 4;
        float res[4];
        #pragma unroll
        for (int k = 0; k < 4; k++) {
            int x = x0 + k;
            float s = 0.f;
            #pragma unroll
            for (int dy = -1; dy <= 1; dy++) {
                int yy = y0 + dy;
                #pragma unroll
                for (int dx = -1; dx <= 1; dx++) {
                    int xx = x + dx;
                    if (yy >= 0 && yy < HH && xx >= 0 && xx < WW)
                        s += wr[(dy+1)*3 + dx+1] * P[yy * WW + xx];
                }
            }
            res[k] = s;
        }
        *(float4*)(op + u * 4) = make_float4(res[0], res[1], res[2], res[3]);
    }
}

// ============================================================
// row L2 norms of q,k rows (channels 0..383 of each qkv), inv = 1/max(||.||,1e-12)
// ============================================================
__global__ __launch_bounds__(256) void rownorm_kernel(const float* __restrict__ qkvx,
    const float* __restrict__ qkvy, float* __restrict__ invx, float* __restrict__ invy)
{
    const int idx = blockIdx.x;         // b*384 + ch
    const int which = blockIdx.y;
    const float* src = which ? qkvy : qkvx;
    const int b = idx / 384, ch = idx % 384;
    const float* row = src + (size_t)b * QKV_B + ch * HWP;
    const int t = threadIdx.x;
    float s = 0.f;
    #pragma unroll
    for (int i = 0; i < 4; i++) {
        float4 v = *(const float4*)(row + (t + 256 * i) * 4);
        s += v.x*v.x + v.y*v.y + v.z*v.z + v.w*v.w;
    }
    #pragma unroll
    for (int off = 32; off > 0; off >>= 1) s += __shfl_down(s, off);
    __shared__ float red[4];
    if ((t & 63) == 0) red[t >> 6] = s;
    __syncthreads();
    if (t == 0) {
        float tot = red[0] + red[1] + red[2] + red[3];
        (which ? invy : invx)[idx] = 1.f / fmaxf(sqrtf(tot), 1e-12f);
    }
}

// ============================================================
// stacked Gram: G(96x96) = [qx;qy] * [kx;ky]^T per (b,h), split-K over n (8 chunks x 512)
// thread grid 16x16, each thread a 6x6 stride-16 micro-tile
// ============================================================
__global__ __launch_bounds__(256) void gram_kernel(const float* __restrict__ qkvx,
    const float* __restrict__ qkvy, float* __restrict__ spart)
{
    __shared__ float Qs[64][97];   // [n_local][row], pad 97 -> conflict-free
    __shared__ float Ks[64][97];
    const int chunk = blockIdx.x, bh = blockIdx.y;
    const int b = bh >> 2, h = bh & 3;
    const int n0 = chunk * 512;
    const int t = threadIdx.x;
    const int tx = t & 15, ty = t >> 4;
    const float* qx = qkvx + (size_t)b * QKV_B + (h * DH) * HWP;
    const float* qy = qkvy + (size_t)b * QKV_B + (h * DH) * HWP;
    const float* kx = qkvx + (size_t)b * QKV_B + (CC + h * DH) * HWP;
    const float* ky = qkvy + (size_t)b * QKV_B + (CC + h * DH) * HWP;
    float acc[6][6] = {};
    for (int ns = 0; ns < 512; ns += 64) {
        #pragma unroll
        for (int i = 0; i < 24; i++) {
            int f = t + 256 * i;           // 96 rows x 64 n
            int r = f >> 6, n = f & 63;
            const float* sq = (r < DH) ? (qx + r * HWP) : (qy + (r - DH) * HWP);
            const float* sk = (r < DH) ? (kx + r * HWP) : (ky + (r - DH) * HWP);
            Qs[n][r] = sq[n0 + ns + n];
            Ks[n][r] = sk[n0 + ns + n];
        }
        __syncthreads();
        for (int n = 0; n < 64; n++) {
            float qv[6], kv[6];
            #pragma unroll
            for (int j = 0; j < 6; j++) qv[j] = Qs[n][ty + 16 * j];
            #pragma unroll
            for (int i = 0; i < 6; i++) kv[i] = Ks[n][tx + 16 * i];
            #pragma unroll
            for (int j = 0; j < 6; j++)
                #pragma unroll
                for (int i = 0; i < 6; i++)
                    acc[j][i] += qv[j] * kv[i];
        }
        __syncthreads();
    }
    float* sp = spart + ((size_t)chunk * 32 + bh) * 9216;
    #pragma unroll
    for (int j = 0; j < 6; j++)
        #pragma unroll
        for (int i = 0; i < 6; i++)
            sp[(ty + 16*j) * 96 + tx + 16*i] = acc[j][i];
}

// ============================================================
// combine split-K partials, scale by invq*invk*temp, softmax per (row, col-half),
// emit quadrant-swizzled coefficient matrix M(96x96):
//  rows 0..47 -> cross coefs [A_du | A_ud], rows 48..95 -> self coefs [A_u | A_d]
// ============================================================
__global__ __launch_bounds__(256) void softmax_kernel(const float* __restrict__ spart,
    const float* __restrict__ invx, const float* __restrict__ invy,
    const float* __restrict__ temp, float* __restrict__ mout)
{
    __shared__ float G[96][97];
    const int bh = blockIdx.x, b = bh >> 2, h = bh & 3;
    const int t = threadIdx.x;
    const float ts = temp[h];
    for (int i = 0; i < 36; i++) {
        int f = t + 256 * i;
        float s = 0.f;
        #pragma unroll
        for (int cch = 0; cch < 8; cch++)
            s += spart[((size_t)cch * 32 + bh) * 9216 + f];
        int r = f / 96, c = f % 96;
        float iq = (r < DH) ? invx[b*384 + h*DH + r] : invy[b*384 + h*DH + (r-DH)];
        float ik = (c < DH) ? invx[b*384 + CC + h*DH + c] : invy[b*384 + CC + h*DH + (c-DH)];
        G[r][c] = s * iq * ik * ts;
    }
    __syncthreads();
    if (t < 192) {                       // 96 rows x 2 col-halves
        int r = t >> 1, hf = t & 1;
        float* rowp = &G[r][hf * DH];
        float m = rowp[0];
        for (int i = 1; i < DH; i++) m = fmaxf(m, rowp[i]);
        float s = 0.f;
        for (int i = 0; i < DH; i++) { float e = __expf(rowp[i] - m); rowp[i] = e; s += e; }
        float inv = 1.f / s;
        for (int i = 0; i < DH; i++) rowp[i] *= inv;
    }
    __syncthreads();
    float* mo = mout + (size_t)bh * 9216;
    for (int i = 0; i < 36; i++) {
        int f = t + 256 * i;
        int r = f / 96, c = f % 96;
        float v;
        if (c < DH) v = (r < DH) ? G[DH + r][c] : G[r - DH][c];
        else        v = G[r][c];
        mo[f] = v;
    }
}

// ============================================================
// output GEMM per (b,h): Out(96 x 4096) = M(96x96) * Vstack(96x4096)
// rows 0..47 -> cross, 48..95 -> self. n-chunks of 128.
// ============================================================
__global__ __launch_bounds__(256) void outmm_kernel(const float* __restrict__ qkvx,
    const float* __restrict__ qkvy, const float* __restrict__ mout, float* __restrict__ out)
{
    __shared__ float Ms[96][97];
    __shared__ float Vs[96][128];
    const int nc = blockIdx.x, bh = blockIdx.y, b = bh >> 2, h = bh & 3;
    const int n0 = nc * 128;
    const int t = threadIdx.x;
    const int tx = t & 31, ty = t >> 5;
    const float* mop = mout + (size_t)bh * 9216;
    for (int i = 0; i < 36; i++) {
        int f = t + 256 * i;
        Ms[f / 96][f % 96] = mop[f];
    }
    #pragma unroll
    for (int i = 0; i < 12; i++) {
        int f = t + 256 * i;            // 96 rows x 32 float4
        int r = f >> 5, c4 = f & 31;
        const float* src = (r < DH)
            ? (qkvx + (size_t)b * QKV_B + (2*CC + h*DH + r) * HWP)
            : (qkvy + (size_t)b * QKV_B + (2*CC + h*DH + (r - DH)) * HWP);
        *(float4*)&Vs[r][c4 * 4] = *(const float4*)(src + n0 + c4 * 4);
    }
    __syncthreads();
    float acc[12][4] = {};
    for (int d = 0; d < 96; d++) {
        float4 v = *(float4*)&Vs[d][tx * 4];
        #pragma unroll
        for (int j = 0; j < 12; j++) {
            float m = Ms[ty + 8 * j][d];
            acc[j][0] += m * v.x; acc[j][1] += m * v.y;
            acc[j][2] += m * v.z; acc[j][3] += m * v.w;
        }
    }
    #pragma unroll
    for (int j = 0; j < 12; j++) {
        int r = ty + 8 * j;
        float* dst = (r < DH)
            ? (out + (size_t)b * X_B + (h*DH + r) * HWP + n0 + tx*4)
            : (out + OUT_HALF + (size_t)b * X_B + (h*DH + (r-DH)) * HWP + n0 + tx*4);
        *(float4*)dst = make_float4(acc[j][0], acc[j][1], acc[j][2], acc[j][3]);
    }
}

// ============================================================
extern "C" void kernel_launch(void* const* d_in, const int* in_sizes, int n_in,
                              void* d_out, int out_size, void* d_ws, size_t ws_size,
                              hipStream_t stream)
{
    const float* x  = (const float*)d_in[0];
    const float* y  = (const float*)d_in[1];
    const float* wq = (const float*)d_in[2];   // (576,192,1,1)
    const float* wd = (const float*)d_in[3];   // (576,1,3,3)
    const float* tp = (const float*)d_in[4];   // (1,4,1,1)
    float* out = (float*)d_out;
    float* ws = (float*)d_ws;

    // ws layout (floats): qkvx | qkvy | t1 (t1 reused for spart/mout/invn)
    float* qkvx = ws;
    float* qkvy = ws + (size_t)BB * QKV_B;
    float* t1   = ws + (size_t)2 * BB * QKV_B;   // needs 3*75.5MB = 226.5MB total
    float* spart = t1;                           // 8*32*9216
    float* mout  = t1 + (size_t)8 * 32 * 9216;   // 32*9216
    float* invx  = mout + (size_t)32 * 9216;     // 3072
    float* invy  = invx + 3072;                  // 3072

    dim3 cgrid(HWP / 128, C3 / 32, BB);
    conv1x1_kernel<<<cgrid, 256, 0, stream>>>(x, wq, t1);
    dw3x3_kernel<<<BB * C3, 256, 0, stream>>>(t1, wd, qkvx);
    conv1x1_kernel<<<cgrid, 256, 0, stream>>>(y, wq, t1);
    dw3x3_kernel<<<BB * C3, 256, 0, stream>>>(t1, wd, qkvy);
    rownorm_kernel<<<dim3(3072, 2), 256, 0, stream>>>(qkvx, qkvy, invx, invy);
    gram_kernel<<<dim3(8, 32), 256, 0, stream>>>(qkvx, qkvy, spart);
    softmax_kernel<<<32, 256, 0, stream>>>(spart, invx, invy, tp, mout);
    outmm_kernel<<<dim3(HWP / 128, 32), 256, 0, stream>>>(qkvx, qkvy, mout, out);
}

// Round 2
// 382.408 us; speedup vs baseline: 1.0832x; 1.0832x over previous
//
#include <hip/hip_runtime.h>

// ---- problem constants ----
#define CC   192                 // C
#define C3   576                 // 3C
#define HH   64
#define WW   64
#define HWP  4096                // H*W
#define BB   8
#define DH   48                  // C/HEADS
#define QKV_B (C3*HWP)           // 2359296 floats per batch of qkv tensor
#define X_B   (CC*HWP)           // 786432 floats per batch of x
#define OUT_HALF ((size_t)BB*X_B)// 6291456

typedef short bf16x8 __attribute__((ext_vector_type(8)));
typedef float f32x4  __attribute__((ext_vector_type(4)));

#define AS1(p) ((__attribute__((address_space(1))) void*)(p))
#define AS3(p) ((__attribute__((address_space(3))) void*)(p))

__device__ __forceinline__ ushort f2bf(float v) {
    union { float f; unsigned u; } a; a.f = v;
    unsigned r = a.u + 0x7FFF + ((a.u >> 16) & 1);   // RNE
    return (ushort)(r >> 16);
}
__device__ __forceinline__ float bf2f(ushort h) {
    union { float f; unsigned u; } a; a.u = ((unsigned)h) << 16; return a.f;
}

// ============================================================
// x (b,192,4096) fp32  ->  XT (b,4096,384) bf16: cols 0..191 = hi, 192..383 = lo
// 64c x 64n transpose tiles via LDS
// ============================================================
__global__ __launch_bounds__(256) void convert_kernel(const float* __restrict__ in,
    ushort* __restrict__ xt)
{
    __shared__ float L[64][65];
    const int n0 = blockIdx.x * 64, c0 = blockIdx.y * 64, b = blockIdx.z;
    const int t = threadIdx.x;
    const float* ip = in + (size_t)b * X_B;
    #pragma unroll
    for (int i = 0; i < 16; i++) {
        int e = t + 256 * i;
        int r = e >> 6, col = e & 63;
        L[r][col] = ip[(size_t)(c0 + r) * HWP + n0 + col];
    }
    __syncthreads();
    #pragma unroll
    for (int i = 0; i < 4; i++) {
        int e = t + 256 * i;              // 1024 units: 64 n x 16 c4
        int n = e >> 4, c4 = e & 15;
        ushort hi[4], lo[4];
        #pragma unroll
        for (int j = 0; j < 4; j++) {
            float v = L[c4 * 4 + j][n];
            hi[j] = f2bf(v);
            lo[j] = f2bf(v - bf2f(hi[j]));
        }
        size_t base = ((size_t)(b * HWP + n0 + n)) * 384 + c0 + c4 * 4;
        *(ushort4*)&xt[base]       = make_ushort4(hi[0], hi[1], hi[2], hi[3]);
        *(ushort4*)&xt[base + 192] = make_ushort4(lo[0], lo[1], lo[2], lo[3]);
    }
}

// ============================================================
// w_qkv (576,192) fp32 -> Wc (640,384) bf16: cols 0..191 = hi, 192..383 = lo,
// rows 576..639 zero padded
// ============================================================
__global__ __launch_bounds__(256) void wconvert_kernel(const float* __restrict__ wq,
    ushort* __restrict__ wc)
{
    int e = (blockIdx.x * 256 + threadIdx.x) * 4;    // 640*384 total
    int oc = e / 384, k = e % 384;
    ushort o[4] = {0, 0, 0, 0};
    if (oc < C3) {
        int kk = (k < 192) ? k : (k - 192);
        #pragma unroll
        for (int j = 0; j < 4; j++) {
            float v = wq[oc * CC + kk + j];
            ushort h = f2bf(v);
            o[j] = (k < 192) ? h : f2bf(v - bf2f(h));
        }
    }
    *(ushort4*)&wc[e] = make_ushort4(o[0], o[1], o[2], o[3]);
}

// ============================================================
// conv1x1 via MFMA: Out(576x4096 per batch) = W(576x192) * X(192x4096), fp32-grade
// via augmented K=576: A' = [Whi | Whi | Wlo] (640x576 padded),
//                      B' = [Xhi ; Xlo ; Xhi] (576x4096)
// tile 128x128, BK=64, 4 waves (2x2 of 64x64), 16x16x32 bf16 MFMA
// LDS via global_load_lds w=16, XOR-swizzled source + reads (bank-conflict-free)
// processes 4 batches per launch (b0 = 0 or 4), out = t1h [4][576][4096]
// ============================================================
__global__ __launch_bounds__(256) void conv1x1_mfma(const ushort* __restrict__ XT,
    const ushort* __restrict__ Wc, float* __restrict__ out, int b0)
{
    __shared__ __align__(16) ushort Asb[128 * 64];
    __shared__ __align__(16) ushort Bsb[128 * 64];
    const int t = threadIdx.x;
    const int lane = t & 63, w = t >> 6;
    const int wm = w >> 1, wn = w & 1;
    const int fr = lane & 15, kg = lane >> 4;
    const int nt = blockIdx.x;
    const int bl = nt >> 5;                    // local batch 0..3
    const int n0 = (nt & 31) * 128;
    const int m0 = blockIdx.y * 128;
    const int bg = b0 + bl;

    f32x4 acc[4][4] = {};
    const int ur = (w) * 64 + lane;            // base unit id within an issue group

    for (int kc = 0; kc < 9; kc++) {
        int kmod = (kc < 3) ? kc : ((kc < 6) ? kc - 3 : kc - 6);
        int cA = ((kc < 6) ? 0 : 192) + kmod * 64;   // A': hi,hi,lo
        int cB = ((kc >= 3 && kc < 6) ? 192 : 0) + kmod * 64; // B': hi,lo,hi
        #pragma unroll
        for (int i = 0; i < 4; i++) {
            int u = i * 256 + ur;              // unit 0..1023 (16B each)
            int r = u >> 3, c = u & 7;
            int cs = c ^ (r & 7);              // pre-swizzled source column
            const ushort* ga = Wc + (size_t)(m0 + r) * 384 + cA + cs * 8;
            __builtin_amdgcn_global_load_lds(AS1(ga), AS3(&Asb[(size_t)(i * 4 + w) * 64 * 8]), 16, 0, 0);
            const ushort* gb = XT + ((size_t)(bg * HWP + n0 + r)) * 384 + cB + cs * 8;
            __builtin_amdgcn_global_load_lds(AS1(gb), AS3(&Bsb[(size_t)(i * 4 + w) * 64 * 8]), 16, 0, 0);
        }
        __syncthreads();
        #pragma unroll
        for (int kq = 0; kq < 8; kq += 4) {
            bf16x8 af[4], bfr[4];
            #pragma unroll
            for (int m = 0; m < 4; m++) {
                int R = wm * 64 + m * 16 + fr;
                int unit = R * 8 + ((kq + kg) ^ (R & 7));
                af[m] = *(const bf16x8*)&Asb[unit * 8];
            }
            #pragma unroll
            for (int n = 0; n < 4; n++) {
                int R = wn * 64 + n * 16 + fr;
                int unit = R * 8 + ((kq + kg) ^ (R & 7));
                bfr[n] = *(const bf16x8*)&Bsb[unit * 8];
            }
            #pragma unroll
            for (int m = 0; m < 4; m++)
                #pragma unroll
                for (int n = 0; n < 4; n++)
                    acc[m][n] = __builtin_amdgcn_mfma_f32_16x16x32_bf16(af[m], bfr[n], acc[m][n], 0, 0, 0);
        }
        __syncthreads();
    }

    float* ob = out + (size_t)bl * QKV_B;
    #pragma unroll
    for (int m = 0; m < 4; m++) {
        int oc = m0 + wm * 64 + m * 16 + kg * 4;
        #pragma unroll
        for (int n = 0; n < 4; n++) {
            int col = n0 + wn * 64 + n * 16 + fr;
            #pragma unroll
            for (int r = 0; r < 4; r++) {
                if (oc + r < C3)
                    ob[(size_t)(oc + r) * HWP + col] = acc[m][n][r];
            }
        }
    }
}

// ============================================================
// depthwise 3x3, pad 1. one block per (b,ch) 64x64 plane staged in LDS
// ============================================================
__global__ __launch_bounds__(256) void dw3x3_kernel(const float* __restrict__ in,
    const float* __restrict__ wd, float* __restrict__ out)
{
    __shared__ float P[HWP];
    const int bc = blockIdx.x;          // b_local*576 + ch
    const int ch = bc % C3;
    const int t = threadIdx.x;
    const float* ip = in + (size_t)bc * HWP;
    float wr[9];
    #pragma unroll
    for (int k = 0; k < 9; k++) wr[k] = wd[ch * 9 + k];
    #pragma unroll
    for (int i = 0; i < 4; i++) {
        int f = t + 256 * i;
        *(float4*)&P[f * 4] = *(const float4*)(ip + f * 4);
    }
    __syncthreads();
    float* op = out + (size_t)bc * HWP;
    #pragma unroll
    for (int i = 0; i < 4; i++) {
        int u = t + 256 * i;            // float4 unit
        int y0 = u >> 4;
        int x0 = (u & 15) * 4;
        float res[4];
        #pragma unroll
        for (int k = 0; k < 4; k++) {
            int x = x0 + k;
            float s = 0.f;
            #pragma unroll
            for (int dy = -1; dy <= 1; dy++) {
                int yy = y0 + dy;
                #pragma unroll
                for (int dx = -1; dx <= 1; dx++) {
                    int xx = x + dx;
                    if (yy >= 0 && yy < HH && xx >= 0 && xx < WW)
                        s += wr[(dy+1)*3 + dx+1] * P[yy * WW + xx];
                }
            }
            res[k] = s;
        }
        *(float4*)(op + u * 4) = make_float4(res[0], res[1], res[2], res[3]);
    }
}

// ============================================================
// row L2 norms of q,k rows, inv = 1/max(||.||,1e-12)
// ============================================================
__global__ __launch_bounds__(256) void rownorm_kernel(const float* __restrict__ qkvx,
    const float* __restrict__ qkvy, float* __restrict__ invx, float* __restrict__ invy)
{
    const int idx = blockIdx.x;         // b*384 + ch
    const int which = blockIdx.y;
    const float* src = which ? qkvy : qkvx;
    const int b = idx / 384, ch = idx % 384;
    const float* row = src + (size_t)b * QKV_B + ch * HWP;
    const int t = threadIdx.x;
    float s = 0.f;
    #pragma unroll
    for (int i = 0; i < 4; i++) {
        float4 v = *(const float4*)(row + (t + 256 * i) * 4);
        s += v.x*v.x + v.y*v.y + v.z*v.z + v.w*v.w;
    }
    #pragma unroll
    for (int off = 32; off > 0; off >>= 1) s += __shfl_down(s, off);
    __shared__ float red[4];
    if ((t & 63) == 0) red[t >> 6] = s;
    __syncthreads();
    if (t == 0) {
        float tot = red[0] + red[1] + red[2] + red[3];
        (which ? invy : invx)[idx] = 1.f / fmaxf(sqrtf(tot), 1e-12f);
    }
}

// ============================================================
// stacked Gram: G(96x96) = [qx;qy] * [kx;ky]^T per (b,h), split-K over n
// ============================================================
__global__ __launch_bounds__(256) void gram_kernel(const float* __restrict__ qkvx,
    const float* __restrict__ qkvy, float* __restrict__ spart)
{
    __shared__ float Qs[64][97];
    __shared__ float Ks[64][97];
    const int chunk = blockIdx.x, bh = blockIdx.y;
    const int b = bh >> 2, h = bh & 3;
    const int n0 = chunk * 512;
    const int t = threadIdx.x;
    const int tx = t & 15, ty = t >> 4;
    const float* qx = qkvx + (size_t)b * QKV_B + (h * DH) * HWP;
    const float* qy = qkvy + (size_t)b * QKV_B + (h * DH) * HWP;
    const float* kx = qkvx + (size_t)b * QKV_B + (CC + h * DH) * HWP;
    const float* ky = qkvy + (size_t)b * QKV_B + (CC + h * DH) * HWP;
    float acc[6][6] = {};
    for (int ns = 0; ns < 512; ns += 64) {
        #pragma unroll
        for (int i = 0; i < 24; i++) {
            int f = t + 256 * i;           // 96 rows x 64 n
            int r = f >> 6, n = f & 63;
            const float* sq = (r < DH) ? (qx + r * HWP) : (qy + (r - DH) * HWP);
            const float* sk = (r < DH) ? (kx + r * HWP) : (ky + (r - DH) * HWP);
            Qs[n][r] = sq[n0 + ns + n];
            Ks[n][r] = sk[n0 + ns + n];
        }
        __syncthreads();
        for (int n = 0; n < 64; n++) {
            float qv[6], kv[6];
            #pragma unroll
            for (int j = 0; j < 6; j++) qv[j] = Qs[n][ty + 16 * j];
            #pragma unroll
            for (int i = 0; i < 6; i++) kv[i] = Ks[n][tx + 16 * i];
            #pragma unroll
            for (int j = 0; j < 6; j++)
                #pragma unroll
                for (int i = 0; i < 6; i++)
                    acc[j][i] += qv[j] * kv[i];
        }
        __syncthreads();
    }
    float* sp = spart + ((size_t)chunk * 32 + bh) * 9216;
    #pragma unroll
    for (int j = 0; j < 6; j++)
        #pragma unroll
        for (int i = 0; i < 6; i++)
            sp[(ty + 16*j) * 96 + tx + 16*i] = acc[j][i];
}

// ============================================================
// combine split-K partials, scale, softmax, emit swizzled coef matrix M(96x96)
// ============================================================
__global__ __launch_bounds__(256) void softmax_kernel(const float* __restrict__ spart,
    const float* __restrict__ invx, const float* __restrict__ invy,
    const float* __restrict__ temp, float* __restrict__ mout)
{
    __shared__ float G[96][97];
    const int bh = blockIdx.x, b = bh >> 2, h = bh & 3;
    const int t = threadIdx.x;
    const float ts = temp[h];
    for (int i = 0; i < 36; i++) {
        int f = t + 256 * i;
        float s = 0.f;
        #pragma unroll
        for (int cch = 0; cch < 8; cch++)
            s += spart[((size_t)cch * 32 + bh) * 9216 + f];
        int r = f / 96, c = f % 96;
        float iq = (r < DH) ? invx[b*384 + h*DH + r] : invy[b*384 + h*DH + (r-DH)];
        float ik = (c < DH) ? invx[b*384 + CC + h*DH + c] : invy[b*384 + CC + h*DH + (c-DH)];
        G[r][c] = s * iq * ik * ts;
    }
    __syncthreads();
    if (t < 192) {
        int r = t >> 1, hf = t & 1;
        float* rowp = &G[r][hf * DH];
        float m = rowp[0];
        for (int i = 1; i < DH; i++) m = fmaxf(m, rowp[i]);
        float s = 0.f;
        for (int i = 0; i < DH; i++) { float e = __expf(rowp[i] - m); rowp[i] = e; s += e; }
        float inv = 1.f / s;
        for (int i = 0; i < DH; i++) rowp[i] *= inv;
    }
    __syncthreads();
    float* mo = mout + (size_t)bh * 9216;
    for (int i = 0; i < 36; i++) {
        int f = t + 256 * i;
        int r = f / 96, c = f % 96;
        float v;
        if (c < DH) v = (r < DH) ? G[DH + r][c] : G[r - DH][c];
        else        v = G[r][c];
        mo[f] = v;
    }
}

// ============================================================
// output GEMM per (b,h): Out(96 x 4096) = M(96x96) * Vstack(96x4096)
// ============================================================
__global__ __launch_bounds__(256) void outmm_kernel(const float* __restrict__ qkvx,
    const float* __restrict__ qkvy, const float* __restrict__ mout, float* __restrict__ out)
{
    __shared__ float Ms[96][97];
    __shared__ float Vs[96][128];
    const int nc = blockIdx.x, bh = blockIdx.y, b = bh >> 2, h = bh & 3;
    const int n0 = nc * 128;
    const int t = threadIdx.x;
    const int tx = t & 31, ty = t >> 5;
    const float* mop = mout + (size_t)bh * 9216;
    for (int i = 0; i < 36; i++) {
        int f = t + 256 * i;
        Ms[f / 96][f % 96] = mop[f];
    }
    #pragma unroll
    for (int i = 0; i < 12; i++) {
        int f = t + 256 * i;
        int r = f >> 5, c4 = f & 31;
        const float* src = (r < DH)
            ? (qkvx + (size_t)b * QKV_B + (2*CC + h*DH + r) * HWP)
            : (qkvy + (size_t)b * QKV_B + (2*CC + h*DH + (r - DH)) * HWP);
        *(float4*)&Vs[r][c4 * 4] = *(const float4*)(src + n0 + c4 * 4);
    }
    __syncthreads();
    float acc[12][4] = {};
    for (int d = 0; d < 96; d++) {
        float4 v = *(float4*)&Vs[d][tx * 4];
        #pragma unroll
        for (int j = 0; j < 12; j++) {
            float m = Ms[ty + 8 * j][d];
            acc[j][0] += m * v.x; acc[j][1] += m * v.y;
            acc[j][2] += m * v.z; acc[j][3] += m * v.w;
        }
    }
    #pragma unroll
    for (int j = 0; j < 12; j++) {
        int r = ty + 8 * j;
        float* dst = (r < DH)
            ? (out + (size_t)b * X_B + (h*DH + r) * HWP + n0 + tx*4)
            : (out + OUT_HALF + (size_t)b * X_B + (h*DH + (r-DH)) * HWP + n0 + tx*4);
        *(float4*)dst = make_float4(acc[j][0], acc[j][1], acc[j][2], acc[j][3]);
    }
}

// ============================================================
extern "C" void kernel_launch(void* const* d_in, const int* in_sizes, int n_in,
                              void* d_out, int out_size, void* d_ws, size_t ws_size,
                              hipStream_t stream)
{
    const float* x  = (const float*)d_in[0];
    const float* y  = (const float*)d_in[1];
    const float* wq = (const float*)d_in[2];   // (576,192,1,1)
    const float* wd = (const float*)d_in[3];   // (576,1,3,3)
    const float* tp = (const float*)d_in[4];   // (1,4,1,1)
    float* out = (float*)d_out;
    float* ws = (float*)d_ws;

    // ws layout (floats): [qkvx 18.9M][qkvy 18.9M][t1h 9.44M][XT 6.29M-eq][Wc]
    float* qkvx = ws;
    float* qkvy = ws + (size_t)BB * QKV_B;
    float* t1h  = ws + (size_t)2 * BB * QKV_B;            // 4 batches of conv out
    ushort* XT  = (ushort*)(t1h + (size_t)4 * QKV_B);     // [8][4096][384] bf16
    ushort* Wc  = XT + (size_t)BB * HWP * 384;            // [640][384] bf16
    // aliases inside t1h (dead after last dw):
    float* spart = t1h;                                   // 8*32*9216
    float* mout  = t1h + (size_t)8 * 32 * 9216;           // 32*9216
    float* invx  = mout + (size_t)32 * 9216;              // 3072
    float* invy  = invx + 3072;                           // 3072

    wconvert_kernel<<<240, 256, 0, stream>>>(wq, Wc);

    // tensor x
    convert_kernel<<<dim3(64, 3, BB), 256, 0, stream>>>(x, XT);
    conv1x1_mfma<<<dim3(128, 5), 256, 0, stream>>>(XT, Wc, t1h, 0);
    dw3x3_kernel<<<4 * C3, 256, 0, stream>>>(t1h, wd, qkvx);
    conv1x1_mfma<<<dim3(128, 5), 256, 0, stream>>>(XT, Wc, t1h, 4);
    dw3x3_kernel<<<4 * C3, 256, 0, stream>>>(t1h, wd, qkvx + (size_t)4 * QKV_B);

    // tensor y
    convert_kernel<<<dim3(64, 3, BB), 256, 0, stream>>>(y, XT);
    conv1x1_mfma<<<dim3(128, 5), 256, 0, stream>>>(XT, Wc, t1h, 0);
    dw3x3_kernel<<<4 * C3, 256, 0, stream>>>(t1h, wd, qkvy);
    conv1x1_mfma<<<dim3(128, 5), 256, 0, stream>>>(XT, Wc, t1h, 4);
    dw3x3_kernel<<<4 * C3, 256, 0, stream>>>(t1h, wd, qkvy + (size_t)4 * QKV_B);

    rownorm_kernel<<<dim3(3072, 2), 256, 0, stream>>>(qkvx, qkvy, invx, invy);
    gram_kernel<<<dim3(8, 32), 256, 0, stream>>>(qkvx, qkvy, spart);
    softmax_kernel<<<32, 256, 0, stream>>>(spart, invx, invy, tp, mout);
    outmm_kernel<<<dim3(HWP / 128, 32), 256, 0, stream>>>(qkvx, qkvy, mout, out);
}

// Round 3
// 291.836 us; speedup vs baseline: 1.4194x; 1.3104x over previous
//
#include <hip/hip_runtime.h>

// ---- problem constants ----
#define CC   192                 // C
#define C3   576                 // 3C
#define HH   64
#define WW   64
#define HWP  4096                // H*W
#define BB   8
#define DH   48                  // C/HEADS
#define QKV_B (C3*HWP)           // floats per batch of conv-out tensor
#define X_B   (CC*HWP)
#define OUT_HALF ((size_t)BB*X_B)

typedef short bf16x8 __attribute__((ext_vector_type(8)));
typedef float f32x4  __attribute__((ext_vector_type(4)));

#define AS1(p) ((__attribute__((address_space(1))) void*)(p))
#define AS3(p) ((__attribute__((address_space(3))) void*)(p))

__device__ __forceinline__ ushort f2bf(float v) {
    union { float f; unsigned u; } a; a.f = v;
    unsigned r = a.u + 0x7FFF + ((a.u >> 16) & 1);   // RNE
    return (ushort)(r >> 16);
}
__device__ __forceinline__ float bf2f(ushort h) {
    union { float f; unsigned u; } a; a.u = ((unsigned)h) << 16; return a.f;
}

// ============================================================
// x (b,192,4096) fp32  ->  XT (b,4096,384) bf16: cols 0..191 hi, 192..383 lo
// ============================================================
__global__ __launch_bounds__(256) void convert_kernel(const float* __restrict__ in,
    ushort* __restrict__ xt)
{
    __shared__ float L[64][65];
    const int n0 = blockIdx.x * 64, c0 = blockIdx.y * 64, b = blockIdx.z;
    const int t = threadIdx.x;
    const float* ip = in + (size_t)b * X_B;
    #pragma unroll
    for (int i = 0; i < 16; i++) {
        int e = t + 256 * i;
        int r = e >> 6, col = e & 63;
        L[r][col] = ip[(size_t)(c0 + r) * HWP + n0 + col];
    }
    __syncthreads();
    #pragma unroll
    for (int i = 0; i < 4; i++) {
        int e = t + 256 * i;
        int n = e >> 4, c4 = e & 15;
        ushort hi[4], lo[4];
        #pragma unroll
        for (int j = 0; j < 4; j++) {
            float v = L[c4 * 4 + j][n];
            hi[j] = f2bf(v);
            lo[j] = f2bf(v - bf2f(hi[j]));
        }
        size_t base = ((size_t)(b * HWP + n0 + n)) * 384 + c0 + c4 * 4;
        *(ushort4*)&xt[base]       = make_ushort4(hi[0], hi[1], hi[2], hi[3]);
        *(ushort4*)&xt[base + 192] = make_ushort4(lo[0], lo[1], lo[2], lo[3]);
    }
}

// ============================================================
// w_qkv -> Wc(640,384) bf16 hi|lo, zero-padded rows
// ============================================================
__global__ __launch_bounds__(256) void wconvert_kernel(const float* __restrict__ wq,
    ushort* __restrict__ wc)
{
    int e = (blockIdx.x * 256 + threadIdx.x) * 4;
    int oc = e / 384, k = e % 384;
    ushort o[4] = {0, 0, 0, 0};
    if (oc < C3) {
        int kk = (k < 192) ? k : (k - 192);
        #pragma unroll
        for (int j = 0; j < 4; j++) {
            float v = wq[oc * CC + kk + j];
            ushort h = f2bf(v);
            o[j] = (k < 192) ? h : f2bf(v - bf2f(h));
        }
    }
    *(ushort4*)&wc[e] = make_ushort4(o[0], o[1], o[2], o[3]);
}

// ============================================================
// conv1x1 via MFMA (proven round-2 kernel, unchanged)
// ============================================================
__global__ __launch_bounds__(256) void conv1x1_mfma(const ushort* __restrict__ XT,
    const ushort* __restrict__ Wc, float* __restrict__ out, int b0)
{
    __shared__ __align__(16) ushort Asb[128 * 64];
    __shared__ __align__(16) ushort Bsb[128 * 64];
    const int t = threadIdx.x;
    const int lane = t & 63, w = t >> 6;
    const int wm = w >> 1, wn = w & 1;
    const int fr = lane & 15, kg = lane >> 4;
    const int nt = blockIdx.x;
    const int bl = nt >> 5;
    const int n0 = (nt & 31) * 128;
    const int m0 = blockIdx.y * 128;
    const int bg = b0 + bl;

    f32x4 acc[4][4] = {};
    const int ur = w * 64 + lane;

    for (int kc = 0; kc < 9; kc++) {
        int kmod = (kc < 3) ? kc : ((kc < 6) ? kc - 3 : kc - 6);
        int cA = ((kc < 6) ? 0 : 192) + kmod * 64;
        int cB = ((kc >= 3 && kc < 6) ? 192 : 0) + kmod * 64;
        #pragma unroll
        for (int i = 0; i < 4; i++) {
            int u = i * 256 + ur;
            int r = u >> 3, c = u & 7;
            int cs = c ^ (r & 7);
            const ushort* ga = Wc + (size_t)(m0 + r) * 384 + cA + cs * 8;
            __builtin_amdgcn_global_load_lds(AS1(ga), AS3(&Asb[(size_t)(i * 4 + w) * 64 * 8]), 16, 0, 0);
            const ushort* gb = XT + ((size_t)(bg * HWP + n0 + r)) * 384 + cB + cs * 8;
            __builtin_amdgcn_global_load_lds(AS1(gb), AS3(&Bsb[(size_t)(i * 4 + w) * 64 * 8]), 16, 0, 0);
        }
        __syncthreads();
        #pragma unroll
        for (int kq = 0; kq < 8; kq += 4) {
            bf16x8 af[4], bfr[4];
            #pragma unroll
            for (int m = 0; m < 4; m++) {
                int R = wm * 64 + m * 16 + fr;
                int unit = R * 8 + ((kq + kg) ^ (R & 7));
                af[m] = *(const bf16x8*)&Asb[unit * 8];
            }
            #pragma unroll
            for (int n = 0; n < 4; n++) {
                int R = wn * 64 + n * 16 + fr;
                int unit = R * 8 + ((kq + kg) ^ (R & 7));
                bfr[n] = *(const bf16x8*)&Bsb[unit * 8];
            }
            #pragma unroll
            for (int m = 0; m < 4; m++)
                #pragma unroll
                for (int n = 0; n < 4; n++)
                    acc[m][n] = __builtin_amdgcn_mfma_f32_16x16x32_bf16(af[m], bfr[n], acc[m][n], 0, 0, 0);
        }
        __syncthreads();
    }

    float* ob = out + (size_t)bl * QKV_B;
    #pragma unroll
    for (int m = 0; m < 4; m++) {
        int oc = m0 + wm * 64 + m * 16 + kg * 4;
        #pragma unroll
        for (int n = 0; n < 4; n++) {
            int col = n0 + wn * 64 + n * 16 + fr;
            #pragma unroll
            for (int r = 0; r < 4; r++) {
                if (oc + r < C3)
                    ob[(size_t)(oc + r) * HWP + col] = acc[m][n][r];
            }
        }
    }
}

// ============================================================
// depthwise 3x3 + fused outputs:
//  ch<384 (q,k): write bf16 hi/lo pair + fused L2-norm scalar
//  ch>=384 (v): write fp32
// padded LDS plane, float4 tap reads, no bounds branches
// ============================================================
__global__ __launch_bounds__(256) void dw3x3_kernel(const float* __restrict__ in,
    const float* __restrict__ wd, ushort* __restrict__ qh, ushort* __restrict__ ql,
    float* __restrict__ vv, float* __restrict__ inv, int b0)
{
    __shared__ float P[66][72];
    const int bc = blockIdx.x;          // bl*576 + ch
    const int bl = bc / C3, ch = bc % C3;
    const int b = b0 + bl;
    const int t = threadIdx.x;
    const float* ip = in + (size_t)bc * HWP;
    float wr[9];
    #pragma unroll
    for (int k = 0; k < 9; k++) wr[k] = wd[ch * 9 + k];
    for (int i = t; i < 66 * 72; i += 256) ((float*)P)[i] = 0.f;
    __syncthreads();
    #pragma unroll
    for (int i = 0; i < 4; i++) {
        int u = t + 256 * i;
        int y = u >> 4, cg = u & 15;
        *(float4*)&P[1 + y][4 + cg * 4] = *(const float4*)(ip + y * WW + cg * 4);
    }
    __syncthreads();

    float ssum = 0.f;
    #pragma unroll
    for (int i = 0; i < 4; i++) {
        int u = t + 256 * i;
        int y0 = u >> 4;
        int x0 = (u & 15) * 4;
        float res[4] = {0.f, 0.f, 0.f, 0.f};
        #pragma unroll
        for (int dy = 0; dy < 3; dy++) {
            float4 A = *(float4*)&P[y0 + dy][x0];
            float4 Bv = *(float4*)&P[y0 + dy][x0 + 4];
            float4 Cv = *(float4*)&P[y0 + dy][x0 + 8];
            float c0 = A.w, c1 = Bv.x, c2 = Bv.y, c3 = Bv.z, c4 = Bv.w, c5 = Cv.x;
            float w0 = wr[dy*3], w1 = wr[dy*3+1], w2 = wr[dy*3+2];
            res[0] += w0*c0 + w1*c1 + w2*c2;
            res[1] += w0*c1 + w1*c2 + w2*c3;
            res[2] += w0*c2 + w1*c3 + w2*c4;
            res[3] += w0*c3 + w1*c4 + w2*c5;
        }
        #pragma unroll
        for (int k = 0; k < 4; k++) ssum += res[k] * res[k];
        if (ch < 384) {
            ushort hi[4], lo[4];
            #pragma unroll
            for (int k = 0; k < 4; k++) {
                hi[k] = f2bf(res[k]);
                lo[k] = f2bf(res[k] - bf2f(hi[k]));
            }
            size_t base = ((size_t)b * 384 + ch) * HWP + u * 4;
            *(ushort4*)&qh[base] = make_ushort4(hi[0], hi[1], hi[2], hi[3]);
            *(ushort4*)&ql[base] = make_ushort4(lo[0], lo[1], lo[2], lo[3]);
        } else {
            *(float4*)&vv[((size_t)b * CC + (ch - 384)) * HWP + u * 4] =
                make_float4(res[0], res[1], res[2], res[3]);
        }
    }
    // fused L2 norm for q,k channels
    if (ch < 384) {
        #pragma unroll
        for (int off = 32; off > 0; off >>= 1) ssum += __shfl_down(ssum, off);
        __shared__ float red[4];
        if ((t & 63) == 0) red[t >> 6] = ssum;
        __syncthreads();
        if (t == 0) {
            float tot = red[0] + red[1] + red[2] + red[3];
            inv[b * 384 + ch] = 1.f / fmaxf(sqrtf(tot), 1e-12f);
        }
    }
}

// ============================================================
// stacked Gram via MFMA: G(96x96) = [qx;qy]*[kx;ky]^T per (b,h),
// 3-term hi/lo (qh*kh + qh*kl + ql*kh), split-K over n (8 chunks x 512)
// 4 waves 2x2 of 48x48, same staging/swizzle pattern as conv1x1_mfma
// ============================================================
__global__ __launch_bounds__(256) void gram_mfma(const ushort* __restrict__ qhx,
    const ushort* __restrict__ qlx, const ushort* __restrict__ qhy,
    const ushort* __restrict__ qly, float* __restrict__ spart)
{
    __shared__ __align__(16) ushort As[96 * 64];
    __shared__ __align__(16) ushort Bs[96 * 64];
    const int chunk = blockIdx.x, bh = blockIdx.y;
    const int b = bh >> 2, h = bh & 3;
    const int t = threadIdx.x;
    const int lane = t & 63, w = t >> 6;
    const int wm = w >> 1, wn = w & 1;
    const int fr = lane & 15, kg = lane >> 4;

    const size_t qbase = ((size_t)b * 384 + h * DH) * HWP;
    const size_t kbase = ((size_t)b * 384 + 192 + h * DH) * HWP;

    f32x4 acc[3][3] = {};

    for (int term = 0; term < 3; term++) {
        const ushort* Aqx = (term == 2) ? qlx : qhx;
        const ushort* Aqy = (term == 2) ? qly : qhy;
        const ushort* Bkx = (term == 1) ? qlx : qhx;
        const ushort* Bky = (term == 1) ? qly : qhy;
        for (int ks = 0; ks < 8; ks++) {
            const int n0 = chunk * 512 + ks * 64;
            #pragma unroll
            for (int i = 0; i < 3; i++) {
                int u = i * 256 + w * 64 + lane;       // unit 0..767
                int r = u >> 3, c = u & 7;
                int cs = c ^ (r & 7);
                const ushort* ga = ((r < DH) ? (Aqx + qbase + (size_t)r * HWP)
                                             : (Aqy + qbase + (size_t)(r - DH) * HWP))
                                   + n0 + cs * 8;
                __builtin_amdgcn_global_load_lds(AS1(ga), AS3(&As[(size_t)(i * 4 + w) * 512]), 16, 0, 0);
                const ushort* gb = ((r < DH) ? (Bkx + kbase + (size_t)r * HWP)
                                             : (Bky + kbase + (size_t)(r - DH) * HWP))
                                   + n0 + cs * 8;
                __builtin_amdgcn_global_load_lds(AS1(gb), AS3(&Bs[(size_t)(i * 4 + w) * 512]), 16, 0, 0);
            }
            __syncthreads();
            #pragma unroll
            for (int kq = 0; kq < 8; kq += 4) {
                bf16x8 af[3], bfr[3];
                #pragma unroll
                for (int m = 0; m < 3; m++) {
                    int R = wm * DH + m * 16 + fr;
                    int unit = R * 8 + ((kq + kg) ^ (R & 7));
                    af[m] = *(const bf16x8*)&As[unit * 8];
                }
                #pragma unroll
                for (int n = 0; n < 3; n++) {
                    int R = wn * DH + n * 16 + fr;
                    int unit = R * 8 + ((kq + kg) ^ (R & 7));
                    bfr[n] = *(const bf16x8*)&Bs[unit * 8];
                }
                #pragma unroll
                for (int m = 0; m < 3; m++)
                    #pragma unroll
                    for (int n = 0; n < 3; n++)
                        acc[m][n] = __builtin_amdgcn_mfma_f32_16x16x32_bf16(af[m], bfr[n], acc[m][n], 0, 0, 0);
            }
            __syncthreads();
        }
    }

    float* sp = spart + ((size_t)chunk * 32 + bh) * 9216;
    #pragma unroll
    for (int m = 0; m < 3; m++) {
        int row = wm * DH + m * 16 + kg * 4;
        #pragma unroll
        for (int n = 0; n < 3; n++) {
            int col = wn * DH + n * 16 + fr;
            #pragma unroll
            for (int r = 0; r < 4; r++)
                sp[(row + r) * 96 + col] = acc[m][n][r];
        }
    }
}

// ============================================================
// combine split-K partials, scale, softmax, emit swizzled coef matrix M(96x96)
// ============================================================
__global__ __launch_bounds__(256) void softmax_kernel(const float* __restrict__ spart,
    const float* __restrict__ invx, const float* __restrict__ invy,
    const float* __restrict__ temp, float* __restrict__ mout)
{
    __shared__ float G[96][97];
    const int bh = blockIdx.x, b = bh >> 2, h = bh & 3;
    const int t = threadIdx.x;
    const float ts = temp[h];
    for (int i = 0; i < 36; i++) {
        int f = t + 256 * i;
        float s = 0.f;
        #pragma unroll
        for (int cch = 0; cch < 8; cch++)
            s += spart[((size_t)cch * 32 + bh) * 9216 + f];
        int r = f / 96, c = f % 96;
        float iq = (r < DH) ? invx[b*384 + h*DH + r] : invy[b*384 + h*DH + (r-DH)];
        float ik = (c < DH) ? invx[b*384 + CC + h*DH + c] : invy[b*384 + CC + h*DH + (c-DH)];
        G[r][c] = s * iq * ik * ts;
    }
    __syncthreads();
    if (t < 192) {
        int r = t >> 1, hf = t & 1;
        float* rowp = &G[r][hf * DH];
        float m = rowp[0];
        for (int i = 1; i < DH; i++) m = fmaxf(m, rowp[i]);
        float s = 0.f;
        for (int i = 0; i < DH; i++) { float e = __expf(rowp[i] - m); rowp[i] = e; s += e; }
        float inv = 1.f / s;
        for (int i = 0; i < DH; i++) rowp[i] *= inv;
    }
    __syncthreads();
    float* mo = mout + (size_t)bh * 9216;
    for (int i = 0; i < 36; i++) {
        int f = t + 256 * i;
        int r = f / 96, c = f % 96;
        float v;
        if (c < DH) v = (r < DH) ? G[DH + r][c] : G[r - DH][c];
        else        v = G[r][c];
        mo[f] = v;
    }
}

// ============================================================
// output GEMM per (b,h): Out(96x4096) = M(96x96)*Vstack(96x4096), fp32
// n-tile 64 -> LDS 61.8KB -> 2 blocks/CU; grid 2048
// ============================================================
__global__ __launch_bounds__(256) void outmm_kernel(const float* __restrict__ vx,
    const float* __restrict__ vy, const float* __restrict__ mout, float* __restrict__ out)
{
    __shared__ float Ms[96][97];
    __shared__ float Vs[96][64];
    const int nc = blockIdx.x, bh = blockIdx.y, b = bh >> 2, h = bh & 3;
    const int n0 = nc * 64;
    const int t = threadIdx.x;
    const int tx = t & 15, ty = t >> 4;
    const float* mop = mout + (size_t)bh * 9216;
    for (int i = 0; i < 36; i++) {
        int f = t + 256 * i;
        Ms[f / 96][f % 96] = mop[f];
    }
    #pragma unroll
    for (int i = 0; i < 6; i++) {
        int f = t + 256 * i;            // 96 rows x 16 float4
        int r = f >> 4, c4 = f & 15;
        const float* src = (r < DH)
            ? (vx + ((size_t)b * CC + h * DH + r) * HWP)
            : (vy + ((size_t)b * CC + h * DH + (r - DH)) * HWP);
        *(float4*)&Vs[r][c4 * 4] = *(const float4*)(src + n0 + c4 * 4);
    }
    __syncthreads();
    float acc[6][4] = {};
    for (int d = 0; d < 96; d++) {
        float4 v = *(float4*)&Vs[d][tx * 4];
        #pragma unroll
        for (int j = 0; j < 6; j++) {
            float m = Ms[ty + 16 * j][d];
            acc[j][0] += m * v.x; acc[j][1] += m * v.y;
            acc[j][2] += m * v.z; acc[j][3] += m * v.w;
        }
    }
    #pragma unroll
    for (int j = 0; j < 6; j++) {
        int r = ty + 16 * j;
        float* dst = (r < DH)
            ? (out + (size_t)b * X_B + (h*DH + r) * HWP + n0 + tx*4)
            : (out + OUT_HALF + (size_t)b * X_B + (h*DH + (r-DH)) * HWP + n0 + tx*4);
        *(float4*)dst = make_float4(acc[j][0], acc[j][1], acc[j][2], acc[j][3]);
    }
}

// ============================================================
extern "C" void kernel_launch(void* const* d_in, const int* in_sizes, int n_in,
                              void* d_out, int out_size, void* d_ws, size_t ws_size,
                              hipStream_t stream)
{
    const float* x  = (const float*)d_in[0];
    const float* y  = (const float*)d_in[1];
    const float* wq = (const float*)d_in[2];
    const float* wd = (const float*)d_in[3];
    const float* tp = (const float*)d_in[4];
    float* out = (float*)d_out;
    float* ws = (float*)d_ws;

    const size_t QKF = 6291456;   // floats per q/k hi-or-lo ushort array
    const size_t VF  = 6291456;   // floats per v fp32 array
    const size_t T1F = 9437184;
    const size_t XTF = 6291456;
    const size_t WCF = 122880;

    ushort* qhx = (ushort*)ws;
    ushort* qlx = (ushort*)(ws + QKF);
    ushort* qhy = (ushort*)(ws + 2 * QKF);
    ushort* qly = (ushort*)(ws + 3 * QKF);
    float*  vx  = ws + 4 * QKF;
    float*  vy  = vx + VF;
    float*  t1h = vy + VF;
    ushort* XT  = (ushort*)(t1h + T1F);
    ushort* Wc  = (ushort*)(t1h + T1F + XTF);
    float*  invx = t1h + T1F + XTF + WCF;
    float*  invy = invx + 3072;
    // spart/mout alias t1h (dead after last dw)
    float* spart = t1h;
    float* mout  = t1h + (size_t)8 * 32 * 9216;

    wconvert_kernel<<<240, 256, 0, stream>>>(wq, Wc);

    // tensor x
    convert_kernel<<<dim3(64, 3, BB), 256, 0, stream>>>(x, XT);
    conv1x1_mfma<<<dim3(128, 5), 256, 0, stream>>>(XT, Wc, t1h, 0);
    dw3x3_kernel<<<4 * C3, 256, 0, stream>>>(t1h, wd, qhx, qlx, vx, invx, 0);
    conv1x1_mfma<<<dim3(128, 5), 256, 0, stream>>>(XT, Wc, t1h, 4);
    dw3x3_kernel<<<4 * C3, 256, 0, stream>>>(t1h, wd, qhx, qlx, vx, invx, 4);

    // tensor y
    convert_kernel<<<dim3(64, 3, BB), 256, 0, stream>>>(y, XT);
    conv1x1_mfma<<<dim3(128, 5), 256, 0, stream>>>(XT, Wc, t1h, 0);
    dw3x3_kernel<<<4 * C3, 256, 0, stream>>>(t1h, wd, qhy, qly, vy, invy, 0);
    conv1x1_mfma<<<dim3(128, 5), 256, 0, stream>>>(XT, Wc, t1h, 4);
    dw3x3_kernel<<<4 * C3, 256, 0, stream>>>(t1h, wd, qhy, qly, vy, invy, 4);

    gram_mfma<<<dim3(8, 32), 256, 0, stream>>>(qhx, qlx, qhy, qly, spart);
    softmax_kernel<<<32, 256, 0, stream>>>(spart, invx, invy, tp, mout);
    outmm_kernel<<<dim3(HWP / 64, 32), 256, 0, stream>>>(vx, vy, mout, out);
}